// Round 14
// baseline (182.800 us; speedup 1.0000x reference)
//
#include <hip/hip_runtime.h>
#include <math.h>

// Problem constants (GroupedKANLayer): B=2, C=31, D=7, H=W=192
#define NBATCH 2
#define NC 31
#define ND 7
#define NH 192
#define NW 192
#define HW (NH * NW)            // 36864
#define NP (NBATCH * HW)        // 73728 pixels
#define NBASIS 8
#define CLEN 56                 // ND * NBASIS
#define KP 70                   // CLEN + ND + ND

#define GWB_N (9 * 80 * 32)             // 23040 bf16 weights, padded

// fused-kernel LDS: compact scoef table 70 rows x 64 px f32 = 17920 B.
// Phase-1 ctx halo B-tile (12672 B) overlays it (disjoint lifetime).
#define SMEM_BYTES (KP * 64 * 4)        // 17920 B
#define B_WORDS (3 * 66 * 32)           // 6336 ushorts (12672 B)

#define KPX 64                  // scoef px stride (f32 words)

typedef __attribute__((ext_vector_type(8))) short s16x8;
typedef __attribute__((ext_vector_type(4))) float f32x4;

__device__ __forceinline__ unsigned short f2bf(float f)
{
    unsigned u = __float_as_uint(f);
    u += 0x7FFFu + ((u >> 16) & 1u);     // round-to-nearest-even
    return (unsigned short)(u >> 16);
}

// ---------------------------------------------------------------------------
// Kernel 1 (tiny): gwb[s][m(80)][ic(32)] = bf16(gw[m][ic][dy][dx]),
// zero-padded. 90 blocks.
// ---------------------------------------------------------------------------
__global__ __launch_bounds__(256) void gwb_kernel(
    const float* __restrict__ gw, unsigned short* __restrict__ gwb)
{
    int e = blockIdx.x * 256 + threadIdx.x;
    if (e < GWB_N) {
        int s  = e / 2560;          // 80*32
        int r  = e - s * 2560;
        int m  = r >> 5;
        int ic = r & 31;
        float v = (m < KP && ic < NC) ? gw[m * (NC * 9) + ic * 9 + s] : 0.f;
        gwb[e] = f2bf(v);
    }
}

// ---------------------------------------------------------------------------
// kan helpers
// ---------------------------------------------------------------------------
__device__ __forceinline__ float spline_part(float xv, const float* cb, int d)
{
    // cardinal cubic B-spline on uniform knots; cb = scoef + lane,
    // coef at LDS word (d*8+jc)*64 + lane -> bank = lane%32 (2-way, free).
    float t = __builtin_fmaf(xv, 2.5f, 5.5f);   // (xv + 2.2) * 2.5
    float fi = floorf(t);
    int i = (int)fi;
    float u = t - fi;
    float u2 = u * u, u3 = u2 * u;
    float um = 1.f - u;
    float w0 = um * um * um * (1.f / 6.f);
    float w3 = u3 * (1.f / 6.f);
    float w1 = (3.f * u3 - 6.f * u2 + 4.f) * (1.f / 6.f);
    float w2 = 1.f - w0 - w1 - w3;          // partition of unity
    int j0 = i - 3;
    float sd = 0.f;
#pragma unroll
    for (int k = 0; k < 4; ++k) {
        int j = j0 + k;
        bool valid = ((unsigned)j) < 8u;
        int jc = j & 7;
        float wk = (k == 0) ? w0 : (k == 1) ? w1 : (k == 2) ? w2 : w3;
        float cf = cb[(d * NBASIS + jc) * KPX];
        sd += (valid ? wk : 0.f) * cf;
    }
    return sd;
}

__device__ __forceinline__ float silu(float xv)
{
    return xv / (1.f + __expf(-xv));
}

// ---------------------------------------------------------------------------
// Kernel 2 (R18 = R10 fused + ctx_mean FOLDED INTO stage-B):
// grid = 1152, block = 256, launch_bounds(256,4) (R16: (256,8) spills).
// The 11us ctx_mean kernel and its 37MB round-trip are eliminated: each
// halo thread reads its 31 ic x 7 d x values directly (217 independent
// loads, one MLP burst, covered by inter-block phase overlap -- the
// mechanism R13 proved is what pays in this kernel) and means them
// in-flight before the bf16 pack. Halo re-reads (~3x) absorbed by L3.
// Phase 1 (conv): 9 accumulated GEMMs M=80,K=32, bf16 MFMA; A-fragments
//   from global gwb (L2-resident); ctx halo B-tile in LDS.
// Phase 2: scatter D-fragments -> scoef[m][px] (17.9 KB, overlays B).
// Phase 3 (kan): 4 waves x 8 channels; 4 channel-pairs/thread, cur/nxt
//   prefetch; pair-0 x loads hoisted above the phase-1 barrier.
// ---------------------------------------------------------------------------
__global__ __launch_bounds__(256, 4) void fused_kernel(
    const unsigned short* __restrict__ gwb, const float* __restrict__ gb,
    const float* __restrict__ x, float* __restrict__ out)
{
    __shared__ __align__(16) unsigned char smem[SMEM_BYTES];
    unsigned short* Bt = (unsigned short*)smem;    // phase 1
    float* scoef = (float*)smem;                   // phases 2-3 (overlay)

    const int tid  = threadIdx.x;
    const int lane = tid & 63;
    const int wv   = tid >> 6;
    const int gr   = blockIdx.x / 3;          // global row 0..383
    const int x0   = (blockIdx.x % 3) * 64;
    const int b    = gr / NH;
    const int y    = gr - b * NH;

    // stage B (ctx-mean fused): thread = halo cell (row 0..2, col 0..65);
    // for each of 31 ic, mean over 7 d of x -> bf16 pack (ic-contiguous,
    // ic=31 padded 0) -> 4 b128 writes.
    if (tid < 3 * 66) {
        int row = tid / 66;
        int col = tid - row * 66;
        int gy = y + row - 1, gx = x0 + col - 1;
        bool ok = (gy >= 0) && (gy < NH) && (gx >= 0) && (gx < NW);
        int cgy = ok ? gy : 0, cgx = ok ? gx : 0;
        const float* src = x + (size_t)(b * NC) * (ND * HW) + cgy * NW + cgx;
        unsigned dw[16];
        if (ok) {
            const float inv7 = 1.0f / 7.0f;
            float v[NC];
#pragma unroll
            for (int ic = 0; ic < NC; ++ic) {
                const float* sc = src + (size_t)ic * (ND * HW);
                float s = sc[0];
#pragma unroll
                for (int d = 1; d < ND; ++d) s += sc[(size_t)d * HW];
                v[ic] = s * inv7;
            }
#pragma unroll
            for (int j = 0; j < 16; ++j) {
                unsigned lo = f2bf(v[2 * j]);
                unsigned hi = (2 * j + 1 < NC) ? (unsigned)f2bf(v[2 * j + 1]) : 0u;
                dw[j] = lo | (hi << 16);
            }
        } else {
#pragma unroll
            for (int j = 0; j < 16; ++j) dw[j] = 0u;
        }
        uint4* dst = (uint4*)(Bt + tid * 32);
#pragma unroll
        for (int q = 0; q < 4; ++q)
            dst[q] = make_uint4(dw[4 * q], dw[4 * q + 1], dw[4 * q + 2], dw[4 * q + 3]);
    }

    // hoist phase-3 pair-0 x loads: HBM latency hides under staging + conv
    const int hw = y * NW + x0 + lane;
    const float* xb = x + (size_t)(b * NC) * (ND * HW) + hw;
    const int c0 = wv * 8;
    float cur[2][ND];
    {
        int ca = min(c0, 30), cb2 = min(c0 + 1, 30);
#pragma unroll
        for (int d = 0; d < ND; ++d) {
            cur[0][d] = xb[((size_t)ca * ND + d) * HW];
            cur[1][d] = xb[((size_t)cb2 * ND + d) * HW];
        }
    }
    __syncthreads();

    // phase 1: MFMA. A row=lane&15, k=(lane>>4)*8+j; B col=lane&15, same k;
    // D col=lane&15, row=(lane>>4)*4+j  (m89-verified layouts).
    const int lm = lane & 15;
    const int kb = lane >> 4;

    f32x4 acc[5];
#pragma unroll
    for (int mt = 0; mt < 5; ++mt)
#pragma unroll
        for (int j = 0; j < 4; ++j) {
            int m = mt * 16 + kb * 4 + j;
            acc[mt][j] = (m < KP) ? gb[m] : 0.f;
        }

    const unsigned short* ap = gwb + lm * 32 + kb * 8;      // GLOBAL (L2)
    const unsigned short* bp = Bt + (wv * 16 + lm) * 32 + kb * 8;

#pragma unroll
    for (int s = 0; s < 9; ++s) {
        const int dy = s / 3, dx = s % 3;
        s16x8 bf = *(const s16x8*)(bp + (dy * 66 + dx) * 32);
#pragma unroll
        for (int mt = 0; mt < 5; ++mt) {
            s16x8 af = *(const s16x8*)(ap + (s * 80 + mt * 16) * 32);
            acc[mt] = __builtin_amdgcn_mfma_f32_16x16x32_bf16(af, bf, acc[mt], 0, 0, 0);
        }
    }
    __syncthreads();            // B dead

    // phase 2: D-fragments -> scoef[m][px], px = wv*16 + lm
    {
        const int px = wv * 16 + lm;
#pragma unroll
        for (int mt = 0; mt < 5; ++mt)
#pragma unroll
            for (int j = 0; j < 4; ++j) {
                int m = mt * 16 + kb * 4 + j;
                if (m < KP) scoef[m * KPX + px] = acc[mt][j];
            }
    }
    __syncthreads();

    // phase 3: kan. lane = px; wave wv covers channels wv*8 .. wv*8+7
    // (clamped to 30; wave 3 computes c30 twice -> same value, benign).
    const float* cbl = scoef + lane;

    float uw[ND], rw[ND];
#pragma unroll
    for (int d = 0; d < ND; ++d) {
        uw[d] = cbl[(CLEN + d) * KPX];
        rw[d] = cbl[(CLEN + ND + d) * KPX];
    }

    float* ob = out + (b * NC) * HW + hw;

    float nxt[2][ND];
#pragma unroll
    for (int pr = 0; pr < 4; ++pr) {
        int ca = min(c0 + 2 * pr, 30), cb2 = min(c0 + 2 * pr + 1, 30);
        if (pr < 3) {
            int na = min(c0 + 2 * pr + 2, 30), nb = min(c0 + 2 * pr + 3, 30);
#pragma unroll
            for (int d = 0; d < ND; ++d) {
                nxt[0][d] = xb[((size_t)na * ND + d) * HW];
                nxt[1][d] = xb[((size_t)nb * ND + d) * HW];
            }
        }
        float sa = 0.f, sb = 0.f;
#pragma unroll
        for (int d = 0; d < ND; ++d) {
            sa += uw[d] * spline_part(cur[0][d], cbl, d) + rw[d] * silu(cur[0][d]);
            sb += uw[d] * spline_part(cur[1][d], cbl, d) + rw[d] * silu(cur[1][d]);
        }
        ob[(size_t)ca * HW] = sa;
        ob[(size_t)cb2 * HW] = sb;
        if (pr < 3) {
#pragma unroll
            for (int d = 0; d < ND; ++d) {
                cur[0][d] = nxt[0][d];
                cur[1][d] = nxt[1][d];
            }
        }
    }
}

// ---------------------------------------------------------------------------
extern "C" void kernel_launch(void* const* d_in, const int* in_sizes, int n_in,
                              void* d_out, int out_size, void* d_ws, size_t ws_size,
                              hipStream_t stream)
{
    const float* x  = (const float*)d_in[0];   // (2,31,7,192,192)
    const float* gw = (const float*)d_in[1];   // (70,31,3,3)
    const float* gb = (const float*)d_in[2];   // (70,)
    float* out = (float*)d_out;                // (2,31,192,192)

    unsigned short* gwb = (unsigned short*)d_ws;   // 46 KB

    gwb_kernel<<<dim3((GWB_N + 255) / 256), 256, 0, stream>>>(gw, gwb);
    fused_kernel<<<dim3(NP / 64), 256, 0, stream>>>(gwb, gb, x, out);
}

// Round 15
// 142.889 us; speedup vs baseline: 1.2793x; 1.2793x over previous
//
#include <hip/hip_runtime.h>
#include <math.h>

// Problem constants (GroupedKANLayer): B=2, C=31, D=7, H=W=192
#define NBATCH 2
#define NC 31
#define ND 7
#define NH 192
#define NW 192
#define HW (NH * NW)            // 36864
#define NP (NBATCH * HW)        // 73728 pixels
#define NBASIS 8
#define CLEN 56                 // ND * NBASIS
#define KP 70                   // CLEN + ND + ND

// ctx_mean grid split: first N4/256 blocks do the mean, next 90 do bf16
// weight transform.
#define N4 (NBATCH * NC * (HW / 4))     // 571392 = 2232 * 256 exactly
#define GWB_N (9 * 80 * 32)             // 23040 bf16 weights, padded

// fused-kernel LDS: compact scoef table 70 rows x 64 px f32 = 17920 B.
// Phase-1 ctx halo B-tile (12672 B) overlays it (disjoint lifetime).
#define SMEM_BYTES (KP * 64 * 4)        // 17920 B
#define B_WORDS (3 * 66 * 32)           // 6336 ushorts (12672 B)

#define KPX 64                  // scoef px stride (f32 words)

typedef __attribute__((ext_vector_type(8))) short s16x8;
typedef __attribute__((ext_vector_type(4))) float f32x4;

__device__ __forceinline__ unsigned short f2bf(float f)
{
    unsigned u = __float_as_uint(f);
    u += 0x7FFFu + ((u >> 16) & 1u);     // round-to-nearest-even
    return (unsigned short)(u >> 16);
}

// ---------------------------------------------------------------------------
// Kernel 1: ctx = mean_d x (float4, 16 B/lane, fully coalesced -- R18
// proved folding this into halo threads costs 150 MB of over-fetch) +
// folded weight transform gwb[s][m(80)][ic(32)].
// ---------------------------------------------------------------------------
__global__ __launch_bounds__(256) void ctx_mean_kernel(
    const float4* __restrict__ x4, float4* __restrict__ ctx4,
    const float* __restrict__ gw, unsigned short* __restrict__ gwb)
{
    const int HW4 = HW / 4;
    int idx = blockIdx.x * 256 + threadIdx.x;
    if (idx < N4) {
        int hw4 = idx % HW4;
        int bc  = idx / HW4;
        const float4* src = x4 + (size_t)bc * (ND * HW4) + hw4;
        float4 a = src[0];
#pragma unroll
        for (int d = 1; d < ND; ++d) {
            float4 v = src[d * HW4];
            a.x += v.x; a.y += v.y; a.z += v.z; a.w += v.w;
        }
        const float inv = 1.0f / 7.0f;
        a.x *= inv; a.y *= inv; a.z *= inv; a.w *= inv;
        ctx4[idx] = a;
        return;
    }
    int e = idx - N4;
    if (e < GWB_N) {
        int s  = e / 2560;          // 80*32
        int r  = e - s * 2560;
        int m  = r >> 5;
        int ic = r & 31;
        float v = (m < KP && ic < NC) ? gw[m * (NC * 9) + ic * 9 + s] : 0.f;
        gwb[e] = f2bf(v);
    }
}

// ---------------------------------------------------------------------------
// kan helpers
// ---------------------------------------------------------------------------
__device__ __forceinline__ float spline_part(float xv, const float* cb, int d)
{
    // cardinal cubic B-spline on uniform knots; cb = scoef + lane,
    // coef at LDS word (d*8+jc)*64 + lane -> bank = lane%32 (2-way, free).
    float t = __builtin_fmaf(xv, 2.5f, 5.5f);   // (xv + 2.2) * 2.5
    float fi = floorf(t);
    int i = (int)fi;
    float u = t - fi;
    float u2 = u * u, u3 = u2 * u;
    float um = 1.f - u;
    float w0 = um * um * um * (1.f / 6.f);
    float w3 = u3 * (1.f / 6.f);
    float w1 = (3.f * u3 - 6.f * u2 + 4.f) * (1.f / 6.f);
    float w2 = 1.f - w0 - w1 - w3;          // partition of unity
    int j0 = i - 3;
    float sd = 0.f;
#pragma unroll
    for (int k = 0; k < 4; ++k) {
        int j = j0 + k;
        bool valid = ((unsigned)j) < 8u;
        int jc = j & 7;
        float wk = (k == 0) ? w0 : (k == 1) ? w1 : (k == 2) ? w2 : w3;
        float cf = cb[(d * NBASIS + jc) * KPX];
        sd += (valid ? wk : 0.f) * cf;
    }
    return sd;
}

__device__ __forceinline__ float silu(float xv)
{
    return xv / (1.f + __expf(-xv));
}

// ---------------------------------------------------------------------------
// Kernel 2 (R19 = R10 fused + 4-WIDE interleaved phase 3):
// grid = 1152, block = 256, launch_bounds(256,4).
// Diagnosis driving this: wall pinned ~46us across occupancy 17-65% and
// VALUBusy 44-58% -> fixed-latency serial skeleton. All prior variants ran
// phase 3 as 2-wide channel-pair chunks; the compiler (48 VGPR) never
// overlaps across chunk boundaries and sinks hoisted loads (R14/R15).
// Fix: make 4 channels' spline chains CONCURRENT IN THE DATAFLOW -- their
// x loads are operands of imminent compute, so the allocator must keep
// them live; per d-step, 4 independent gather+FMA chains interleave.
// 2 chunks instead of 4. Expected VGPR ~90 (<=128 cap of (256,4)).
// Phase 1 (conv): 9 accumulated GEMMs M=80,K=32, bf16 MFMA; A-fragments
//   from global gwb (L2-resident); ctx halo B-tile in LDS.
// Phase 2: scatter D-fragments -> scoef[m][px] (17.9 KB, overlays B).
// Phase 3 (kan): 4 waves x 8 channels as 2x 4-wide chunks; chunk-B x
//   loads issued before chunk-A compute (covered by it).
// ---------------------------------------------------------------------------
__global__ __launch_bounds__(256, 4) void fused_kernel(
    const float* __restrict__ ctx, const unsigned short* __restrict__ gwb,
    const float* __restrict__ gb, const float* __restrict__ x,
    float* __restrict__ out)
{
    __shared__ __align__(16) unsigned char smem[SMEM_BYTES];
    unsigned short* Bt = (unsigned short*)smem;    // phase 1
    float* scoef = (float*)smem;                   // phases 2-3 (overlay)

    const int tid  = threadIdx.x;
    const int lane = tid & 63;
    const int wv   = tid >> 6;
    const int gr   = blockIdx.x / 3;          // global row 0..383
    const int x0   = (blockIdx.x % 3) * 64;
    const int b    = gr / NH;
    const int y    = gr - b * NH;

    // stage B: thread = halo cell (row 0..2, col 0..65); 31 strided ctx
    // reads -> bf16 pack (ic-contiguous, ic=31 padded 0) -> 4 b128 writes.
    if (tid < 3 * 66) {
        int row = tid / 66;
        int col = tid - row * 66;
        int gy = y + row - 1, gx = x0 + col - 1;
        bool ok = (gy >= 0) && (gy < NH) && (gx >= 0) && (gx < NW);
        int cgy = ok ? gy : 0, cgx = ok ? gx : 0;
        const float* src = ctx + (size_t)(b * NC) * HW + cgy * NW + cgx;
        unsigned dw[16];
        if (ok) {
            float v[NC];
#pragma unroll
            for (int ic = 0; ic < NC; ++ic) v[ic] = src[(size_t)ic * HW];
#pragma unroll
            for (int j = 0; j < 16; ++j) {
                unsigned lo = f2bf(v[2 * j]);
                unsigned hi = (2 * j + 1 < NC) ? (unsigned)f2bf(v[2 * j + 1]) : 0u;
                dw[j] = lo | (hi << 16);
            }
        } else {
#pragma unroll
            for (int j = 0; j < 16; ++j) dw[j] = 0u;
        }
        uint4* dst = (uint4*)(Bt + tid * 32);
#pragma unroll
        for (int q = 0; q < 4; ++q)
            dst[q] = make_uint4(dw[4 * q], dw[4 * q + 1], dw[4 * q + 2], dw[4 * q + 3]);
    }

    // hoist chunk-A pair-0 x loads above the barrier (covered by staging)
    const int hw = y * NW + x0 + lane;
    const float* xb = x + (size_t)(b * NC) * (ND * HW) + hw;
    const int c0 = wv * 8;
    const int cA0 = min(c0 + 0, 30), cA1 = min(c0 + 1, 30);
    const int cA2 = min(c0 + 2, 30), cA3 = min(c0 + 3, 30);
    const int cB0 = min(c0 + 4, 30), cB1 = min(c0 + 5, 30);
    const int cB2 = min(c0 + 6, 30), cB3 = min(c0 + 7, 30);

    float xA0[ND], xA1[ND];
#pragma unroll
    for (int d = 0; d < ND; ++d) {
        xA0[d] = xb[((size_t)cA0 * ND + d) * HW];
        xA1[d] = xb[((size_t)cA1 * ND + d) * HW];
    }
    __syncthreads();

    // phase 1: MFMA. A row=lane&15, k=(lane>>4)*8+j; B col=lane&15, same k;
    // D col=lane&15, row=(lane>>4)*4+j  (m89-verified layouts).
    const int lm = lane & 15;
    const int kb = lane >> 4;

    f32x4 acc[5];
#pragma unroll
    for (int mt = 0; mt < 5; ++mt)
#pragma unroll
        for (int j = 0; j < 4; ++j) {
            int m = mt * 16 + kb * 4 + j;
            acc[mt][j] = (m < KP) ? gb[m] : 0.f;
        }

    const unsigned short* ap = gwb + lm * 32 + kb * 8;      // GLOBAL (L2)
    const unsigned short* bp = Bt + (wv * 16 + lm) * 32 + kb * 8;

#pragma unroll
    for (int s = 0; s < 9; ++s) {
        const int dy = s / 3, dx = s % 3;
        s16x8 bf = *(const s16x8*)(bp + (dy * 66 + dx) * 32);
#pragma unroll
        for (int mt = 0; mt < 5; ++mt) {
            s16x8 af = *(const s16x8*)(ap + (s * 80 + mt * 16) * 32);
            acc[mt] = __builtin_amdgcn_mfma_f32_16x16x32_bf16(af, bf, acc[mt], 0, 0, 0);
        }
    }
    __syncthreads();            // B dead

    // phase 2: D-fragments -> scoef[m][px], px = wv*16 + lm
    {
        const int px = wv * 16 + lm;
#pragma unroll
        for (int mt = 0; mt < 5; ++mt)
#pragma unroll
            for (int j = 0; j < 4; ++j) {
                int m = mt * 16 + kb * 4 + j;
                if (m < KP) scoef[m * KPX + px] = acc[mt][j];
            }
    }
    __syncthreads();

    // phase 3: kan, 4-wide chunks. lane = px; wave wv covers c0..c0+7.
    const float* cbl = scoef + lane;

    // complete chunk A's x (cA2, cA3) + issue chunk B's x upfront
    float xA2[ND], xA3[ND];
#pragma unroll
    for (int d = 0; d < ND; ++d) {
        xA2[d] = xb[((size_t)cA2 * ND + d) * HW];
        xA3[d] = xb[((size_t)cA3 * ND + d) * HW];
    }
    float xB0[ND], xB1[ND], xB2[ND], xB3[ND];
#pragma unroll
    for (int d = 0; d < ND; ++d) {
        xB0[d] = xb[((size_t)cB0 * ND + d) * HW];
        xB1[d] = xb[((size_t)cB1 * ND + d) * HW];
        xB2[d] = xb[((size_t)cB2 * ND + d) * HW];
        xB3[d] = xb[((size_t)cB3 * ND + d) * HW];
    }

    float uw[ND], rw[ND];
#pragma unroll
    for (int d = 0; d < ND; ++d) {
        uw[d] = cbl[(CLEN + d) * KPX];
        rw[d] = cbl[(CLEN + ND + d) * KPX];
    }

    float* ob = out + (b * NC) * HW + hw;

    // chunk A: 4 concurrent spline chains per d-step
    {
        float s0 = 0.f, s1 = 0.f, s2 = 0.f, s3 = 0.f;
#pragma unroll
        for (int d = 0; d < ND; ++d) {
            s0 += uw[d] * spline_part(xA0[d], cbl, d) + rw[d] * silu(xA0[d]);
            s1 += uw[d] * spline_part(xA1[d], cbl, d) + rw[d] * silu(xA1[d]);
            s2 += uw[d] * spline_part(xA2[d], cbl, d) + rw[d] * silu(xA2[d]);
            s3 += uw[d] * spline_part(xA3[d], cbl, d) + rw[d] * silu(xA3[d]);
        }
        ob[(size_t)cA0 * HW] = s0;
        ob[(size_t)cA1 * HW] = s1;
        ob[(size_t)cA2 * HW] = s2;
        ob[(size_t)cA3 * HW] = s3;
    }
    // chunk B
    {
        float s0 = 0.f, s1 = 0.f, s2 = 0.f, s3 = 0.f;
#pragma unroll
        for (int d = 0; d < ND; ++d) {
            s0 += uw[d] * spline_part(xB0[d], cbl, d) + rw[d] * silu(xB0[d]);
            s1 += uw[d] * spline_part(xB1[d], cbl, d) + rw[d] * silu(xB1[d]);
            s2 += uw[d] * spline_part(xB2[d], cbl, d) + rw[d] * silu(xB2[d]);
            s3 += uw[d] * spline_part(xB3[d], cbl, d) + rw[d] * silu(xB3[d]);
        }
        ob[(size_t)cB0 * HW] = s0;
        ob[(size_t)cB1 * HW] = s1;
        ob[(size_t)cB2 * HW] = s2;
        ob[(size_t)cB3 * HW] = s3;
    }
}

// ---------------------------------------------------------------------------
extern "C" void kernel_launch(void* const* d_in, const int* in_sizes, int n_in,
                              void* d_out, int out_size, void* d_ws, size_t ws_size,
                              hipStream_t stream)
{
    const float* x  = (const float*)d_in[0];   // (2,31,7,192,192)
    const float* gw = (const float*)d_in[1];   // (70,31,3,3)
    const float* gb = (const float*)d_in[2];   // (70,)
    float* out = (float*)d_out;                // (2,31,192,192)

    float* ctx = (float*)d_ws;                             // 9.1 MB
    unsigned short* gwb = (unsigned short*)(ctx + (size_t)NBATCH * NC * HW);

    ctx_mean_kernel<<<dim3(N4 / 256 + (GWB_N + 255) / 256), 256, 0, stream>>>(
        (const float4*)x, (float4*)ctx, gw, gwb);
    fused_kernel<<<dim3(NP / 64), 256, 0, stream>>>(ctx, gwb, gb, x, out);
}